// Round 14
// baseline (144.462 us; speedup 1.0000x reference)
//
#include <hip/hip_runtime.h>
#include <stdint.h>

// BATCH=4096, LENGTH=128, FEAT=4, RANK=64, 126 mid sites.
#define NSITES 126
#define XPITCH 516                 // xbuf row pitch (floats)
#define VPH    72                  // vbuf row pitch (halfs): 144B rows

// dynamic LDS carve: ring 3x32KB | xbuf 16*516*4 | vbuf 2*16*72*2 | eacc
#define RING_B   98304
#define XBUF_OFF 98304
#define VBUF_OFF 131328            // 98304 + 33024 (16-aligned)
#define EACC_OFF 135936
#define SMEM_B   136000

typedef _Float16 half8_t  __attribute__((ext_vector_type(8)));
typedef float    float4_t __attribute__((ext_vector_type(4)));

// light barrier: LDS-only drain; DMA loads (vmcnt) stay in flight across it
#define LBAR() asm volatile("s_waitcnt lgkmcnt(0)\n\ts_barrier" ::: "memory")
// explicit waits
#define WAITV(N) asm volatile("s_waitcnt vmcnt(" #N ")" ::: "memory")
#define WAITL()  asm volatile("s_waitcnt lgkmcnt(0)" ::: "memory")

// global->LDS DMA, 16B/lane: LDS dest = wave-uniform base + lane*16 (linear),
// global src = per-lane. R7-verified mechanism (passed, bit-identical).
__device__ __forceinline__ void gstage16(const void* g, void* l) {
    __builtin_amdgcn_global_load_lds(
        (const __attribute__((address_space(1))) void*)g,
        (__attribute__((address_space(3))) void*)l, 16, 0, 0);
}
__device__ __forceinline__ uint32_t lds_off(const void* p) {
    return (uint32_t)(uintptr_t)(const __attribute__((address_space(3))) void*)p;
}
// asm LDS read, compile-time offset imm: manual lgkm ledger (R7-verified)
__device__ __forceinline__ void lread(half8_t& d, uint32_t base, int imm) {
    asm volatile("ds_read_b128 %0, %1 offset:%c2" : "=v"(d) : "v"(base), "i"(imm));
}

// ---------------------------------------------------------------------------
// Repack mid_cores fp32 [126][64][4][64] -> fp16 fragments, frag F (16B):
// element j = G[l = 32h + 8q + j][n = i*64 + w*16 + c], lane = 16q + c,
// F = ((i*2+h)*4 + w)*64 + lane  (+ s*2048). HW-verified (R0/R3/R7-R13).
// ---------------------------------------------------------------------------
__global__ __launch_bounds__(256) void repack_g(const float* __restrict__ mid,
                                                _Float16* __restrict__ gt) {
    const int F = blockIdx.x * 256 + threadIdx.x;          // 0..258047 == 126*2048
    const int lane = F & 63, w = (F >> 6) & 3, h = (F >> 8) & 1, i = (F >> 9) & 3;
    const int s = F >> 11;
    const int q = lane >> 4, c = lane & 15;
    const float* src = mid + (size_t)s * 16384 + (32 * h + 8 * q) * 256 + i * 64 + w * 16 + c;
    half8_t o;
#pragma unroll
    for (int j = 0; j < 8; ++j) o[j] = (_Float16)src[j * 256];
    ((half8_t*)gt)[F] = o;
}

// ---------------------------------------------------------------------------
// Main chain: 256 blocks x 256 threads (1 block/CU, 16 batches/CU, 4 waves).
// R14 delta vs R8 (single variable): G delivery via global_load_lds DMA into
// a 3-slot LDS ring instead of global->VGPR loads. Rationale: measured
// VGPR-return cap ~27-30 B/cyc/CU across R0/R8/R11/R13 regardless of
// geometry/lead; the DMA pipe sustains >50 B/cyc/CU (m97 GEMM ladder).
// Per window s: [issue 8 DMA for site s+2 into slot (s+2)%3] -> STEP s
// (reads own 8KB strip from slot s%3 via asm ds_read; af/xs/renorm/MFMA/
// combine byte-for-byte R8) -> WAITV(8) (site s+1's batch lands) -> LBAR.
// Each wave DMAs and reads ONLY its own strip (ih*4096 + wv*1024 + lane*16).
// ---------------------------------------------------------------------------
__global__ __launch_bounds__(256, 1) void tt_chain(
    const float* __restrict__ x,      // [4096][128][4]
    const float* __restrict__ first,  // [4][64]
    const float* __restrict__ last,   // [64][4]
    const _Float16* __restrict__ gt,  // frag-ordered fp16, 32 KB/site
    float* __restrict__ out) {        // [4096]

    extern __shared__ __align__(16) char smem[];
    char*     ring = smem;
    float*    xbuf = (float*)(smem + XBUF_OFF);
    _Float16* vbuf = (_Float16*)(smem + VBUF_OFF);   // [2][16*VPH]
    int*      eacc = (int*)(smem + EACC_OFF);

    const int tid  = threadIdx.x;
    const int wv   = tid >> 6;        // wave 0..3: owns r-cols [16wv,16wv+16)
    const int lane = tid & 63;
    const int q    = lane >> 4;
    const int c    = lane & 15;
    const int b0   = blockIdx.x * 16;

    // stage x: 16 rows x 512 floats, coalesced (plain loads, pre-ledger)
    {
        const int bb = tid >> 4, seg = tid & 15;
        const float4_t* src = (const float4_t*)(x + (size_t)(b0 + bb) * 512 + seg * 32);
        float4_t* dst = (float4_t*)(xbuf + bb * XPITCH + seg * 32);
#pragma unroll
        for (int k = 0; k < 8; ++k) dst[k] = src[k];
    }
    if (tid < 16) eacc[tid] = 0;
    __syncthreads();

    // v0[b,r] = sum_i x[b,0,i] * first[i,r]  (fp16 store) — verbatim R8
    {
        const int bb = tid >> 4, rq = tid & 15;
        const float xs0 = xbuf[bb * XPITCH + 0], xs1 = xbuf[bb * XPITCH + 1];
        const float xs2 = xbuf[bb * XPITCH + 2], xs3 = xbuf[bb * XPITCH + 3];
#pragma unroll
        for (int k = 0; k < 4; ++k) {
            const int r = rq * 4 + k;
            vbuf[bb * VPH + r] = (_Float16)(
                xs0 * first[r] + xs1 * first[64 + r] + xs2 * first[128 + r] + xs3 * first[192 + r]);
        }
    }

    // zero the vmcnt ledger: all plain VMEM above drained; from here the only
    // in-loop VMEM is our DMA -> counts exact.
    WAITV(0);

    // DMA issue: wave wv stages its own strip of site `site` into slot `slot`
    const uint32_t ring0 = lds_off(ring);
    auto ISSUE = [&](int site, int slot) {
        const char* gp = (const char*)gt + (size_t)site * 32768 + wv * 1024 + lane * 16;
        char* lp = ring + slot * 32768 + wv * 1024;          // + lane*16 by HW
#pragma unroll
        for (int ih = 0; ih < 8; ++ih) gstage16(gp + ih * 4096, lp + ih * 4096);
    };

    // prologue: sites 0,1 in flight (16 DMA), site 0 drained before loop
    ISSUE(0, 0);
    ISSUE(1, 1);
    WAITV(8);       // site 0 resident in slot 0
    LBAR();         // vbuf[0] visible to all waves

    auto STEP = [&](int s, int slot) {
        const int p = s & 1;

        // af + xs reads (LDS, compiler-tracked) — verbatim R8
        const _Float16* vr = &vbuf[p * (16 * VPH) + c * VPH];
        half8_t af0 = *(const half8_t*)(vr + q * 8);          // v[c][8q..8q+7]
        half8_t af1 = *(const half8_t*)(vr + 32 + q * 8);     // v[c][32+8q..]
        float4_t xs[4];
#pragma unroll
        for (int jj = 0; jj < 4; ++jj)
            xs[jj] = *(const float4_t*)(xbuf + (q * 4 + jj) * XPITCH + (s + 1) * 4);

        // G frags from this wave's strip of the ring slot (asm ds_read)
        const uint32_t gb = ring0 + slot * 32768 + wv * 1024 + lane * 16;
        half8_t g[8];
#pragma unroll
        for (int ih = 0; ih < 8; ++ih) lread(g[ih], gb, ih * 4096);
        WAITL();                              // af, xs, g all retired
        __builtin_amdgcn_sched_barrier(0);    // rule #18: pin MFMAs below

        // wave-local per-batch power-of-2 renorm every 8 sites — verbatim R8
        if ((s & 7) == 0 && s != 0) {
            float a[16];
#pragma unroll
            for (int k = 0; k < 8; ++k) { a[k] = (float)af0[k]; a[8 + k] = (float)af1[k]; }
            float m = 0.f;
#pragma unroll
            for (int k = 0; k < 16; ++k) m = fmaxf(m, fabsf(a[k]));
            m = fmaxf(m, __shfl_xor(m, 16));   // max over q: all 64 r per batch
            m = fmaxf(m, __shfl_xor(m, 32));
            int e = 0;
            if (m > 0.f) frexpf(m, &e);
            const float sc = ldexpf(1.0f, -e);
#pragma unroll
            for (int k = 0; k < 8; ++k) {
                af0[k] = (_Float16)(a[k] * sc);
                af1[k] = (_Float16)(a[8 + k] * sc);
            }
            if (tid < 16) eacc[tid] += e;   // wave 0, q=0: lane==c==batch
        }

        float4_t acc[4];
#pragma unroll
        for (int i = 0; i < 4; ++i) {
            float4_t z = {0.f, 0.f, 0.f, 0.f};
            z = __builtin_amdgcn_mfma_f32_16x16x32_f16(af0, g[i * 2 + 0], z, 0, 0, 0);
            z = __builtin_amdgcn_mfma_f32_16x16x32_f16(af1, g[i * 2 + 1], z, 0, 0, 0);
            acc[i] = z;
        }

#pragma unroll
        for (int jj = 0; jj < 4; ++jj) {
            const float vn = xs[jj].x * acc[0][jj] + xs[jj].y * acc[1][jj] +
                             xs[jj].z * acc[2][jj] + xs[jj].w * acc[3][jj];
            vbuf[(p ^ 1) * (16 * VPH) + (q * 4 + jj) * VPH + wv * 16 + c] = (_Float16)vn;
        }
    };

    for (int s = 0; s < NSITES; ++s) {
        // issue site s+2 (clamped dup at tail: written to a retired slot,
        // never read, drained by the final WAITV(0))
        const int sn = (s + 2 < NSITES) ? s + 2 : NSITES - 1;
        ISSUE(sn, (s + 2) % 3);
        STEP(s, s % 3);
        // outstanding 16; keep newest 8 -> site s+1's batch resident
        WAITV(8);
        LBAR();
    }
    WAITV(0);   // drain tail dups

    // final v in vbuf parity 0 (126 even); out[b] = 2^eacc * sum_r v*last_vec
    {
        const int bb = tid >> 4, rq = tid & 15;
        const float x0 = xbuf[bb * XPITCH + 508], x1 = xbuf[bb * XPITCH + 509];
        const float x2 = xbuf[bb * XPITCH + 510], x3 = xbuf[bb * XPITCH + 511];
        float dot = 0.f;
#pragma unroll
        for (int k = 0; k < 4; ++k) {
            const int r = rq * 4 + k;
            const float lv = last[r * 4 + 0] * x0 + last[r * 4 + 1] * x1 +
                             last[r * 4 + 2] * x2 + last[r * 4 + 3] * x3;
            dot += lv * (float)vbuf[bb * VPH + r];
        }
#pragma unroll
        for (int o = 8; o > 0; o >>= 1) dot += __shfl_xor(dot, o, 16);
        if (rq == 0) out[b0 + bb] = ldexpf(dot, eacc[bb]);
    }
}

extern "C" void kernel_launch(void* const* d_in, const int* in_sizes, int n_in,
                              void* d_out, int out_size, void* d_ws, size_t ws_size,
                              hipStream_t stream) {
    (void)in_sizes; (void)n_in; (void)out_size; (void)ws_size;
    const float* x     = (const float*)d_in[0];
    const float* first = (const float*)d_in[1];
    const float* mid   = (const float*)d_in[2];
    const float* last  = (const float*)d_in[3];
    float* out = (float*)d_out;
    _Float16* gt = (_Float16*)d_ws;   // 126*2048*16 B = 4,128,768 B

    // allow 136 KB dynamic LDS (gfx950: 160 KB/CU; HK kernels use 128 KB)
    hipFuncSetAttribute((const void*)tt_chain,
                        hipFuncAttributeMaxDynamicSharedMemorySize, SMEM_B);

    repack_g<<<1008, 256, 0, stream>>>(mid, gt);
    tt_chain<<<256, 256, SMEM_B, stream>>>(x, first, last, gt, out);
}

// Round 15
// 110.650 us; speedup vs baseline: 1.3056x; 1.3056x over previous
//
#include <hip/hip_runtime.h>
#include <stdint.h>

// BATCH=4096, LENGTH=128, FEAT=4, RANK=64, 126 mid sites.
#define NSITES 126
#define XPITCH 516                 // xbuf row pitch (floats)
#define VPH    72                  // vbuf row pitch (halfs): 144B rows

typedef _Float16 half8_t  __attribute__((ext_vector_type(8)));
typedef float    float4_t __attribute__((ext_vector_type(4)));

// light barrier: LDS-only drain; asm G-loads (vmcnt) stay in flight across it
#define LBAR() asm volatile("s_waitcnt lgkmcnt(0)\n\ts_barrier" ::: "memory")
// explicit wait: oldest loads complete when <=N remain outstanding
#define WAITV(N) asm volatile("s_waitcnt vmcnt(" #N ")" ::: "memory")
// zero-instruction tie: forces the 8 frag values through a volatile asm node,
// so MFMAs (pure ops) cannot be scheduled above the preceding WAITV
#define TIE8(F) asm volatile("" : "+v"(F[0]), "+v"(F[1]), "+v"(F[2]), "+v"(F[3]), \
                                  "+v"(F[4]), "+v"(F[5]), "+v"(F[6]), "+v"(F[7]))

// volatile asm load — R0/R8/R11-proven form: full 64-bit VGPR address pair.
// (R12 showed nt demotes L2 residency: −21%; R14 showed DMA is slower still.)
__device__ __forceinline__ void aload(half8_t& d, const void* p) {
    asm volatile("global_load_dwordx4 %0, %1, off" : "=v"(d) : "v"(p));
}

// ---------------------------------------------------------------------------
// Repack mid_cores fp32 [126][64][4][64] -> fp16 fragments, frag F (16B):
// element j = G[l = 32h + 8q + j][n = i*64 + w*16 + c], lane = 16q + c,
// F = ((i*2+h)*4 + w)*64 + lane  (+ s*2048). HW-verified (R0/R3/R7-R14).
// ---------------------------------------------------------------------------
__global__ __launch_bounds__(256) void repack_g(const float* __restrict__ mid,
                                                _Float16* __restrict__ gt) {
    const int F = blockIdx.x * 256 + threadIdx.x;          // 0..258047 == 126*2048
    const int lane = F & 63, w = (F >> 6) & 3, h = (F >> 8) & 1, i = (F >> 9) & 3;
    const int s = F >> 11;
    const int q = lane >> 4, c = lane & 15;
    const float* src = mid + (size_t)s * 16384 + (32 * h + 8 * q) * 256 + i * 64 + w * 16 + c;
    half8_t o;
#pragma unroll
    for (int j = 0; j < 8; ++j) o[j] = (_Float16)src[j * 256];
    ((half8_t*)gt)[F] = o;
}

// ---------------------------------------------------------------------------
// Main chain — FINAL (R11 configuration, the measured optimum):
// 256 blocks x 512 threads (1 block/CU, 16 batches/CU, 8 waves = 2 teams of
// 4). Team T = w>>2 runs STEP for sites s%2==T (its wave wv = w&3 owns r-cols
// [16wv,16wv+16)); on off-windows it runs PREP: its next stride-2 G 8-load +
// xs pre-read into registers. One LBAR per site for all 8 waves. Per-team
// ledger: 3 rotating 8-frag buffers, 24 outstanding at each WAITV(16).
// This sits at the measured per-CU L2-streaming roofline: 32KB/site at
// ~29.4 B/cyc/CU -> 1115 cyc/site (floor ~1100). Delivery-path triangulation
// (R11/R12/R13/R14: reg/nt/half-CU/DMA = 29/24/27/21 B/cyc) shows the cap is
// the CU's VMEM return throughput, not geometry, cache policy, or pipe.
// ---------------------------------------------------------------------------
__global__ __launch_bounds__(512, 2) void tt_chain(
    const float* __restrict__ x,      // [4096][128][4]
    const float* __restrict__ first,  // [4][64]
    const float* __restrict__ last,   // [64][4]
    const _Float16* __restrict__ gt,  // frag-ordered fp16, 32 KB/site
    float* __restrict__ out) {        // [4096]

    __shared__ __align__(16) _Float16 vbuf[2][16 * VPH];
    __shared__ float xbuf[16 * XPITCH];
    __shared__ int   eacc[16];

    const int tid  = threadIdx.x;
    const int w    = tid >> 6;        // 0..7
    const int team = w >> 2;          // 0: even sites, 1: odd sites
    const int wv   = w & 3;           // r-col group within team
    const int lane = tid & 63;
    const int q    = lane >> 4;
    const int c    = lane & 15;
    const int b0   = blockIdx.x * 16;

    // stage x: 16 rows x 512 floats, coalesced across 512 threads
    {
        const int bb = tid >> 5, seg = tid & 31;
        const float4_t* src = (const float4_t*)(x + (size_t)(b0 + bb) * 512);
        float4_t* dst = (float4_t*)(xbuf + bb * XPITCH);
#pragma unroll
        for (int k = 0; k < 4; ++k) dst[seg + 32 * k] = src[seg + 32 * k];
    }
    if (tid < 16) eacc[tid] = 0;
    __syncthreads();

    // v0[b,r] = sum_i x[b,0,i] * first[i,r]  (fp16 store)
    if (tid < 256) {
        const int bb = tid >> 4, rq = tid & 15;
        const float xs0 = xbuf[bb * XPITCH + 0], xs1 = xbuf[bb * XPITCH + 1];
        const float xs2 = xbuf[bb * XPITCH + 2], xs3 = xbuf[bb * XPITCH + 3];
#pragma unroll
        for (int k = 0; k < 4; ++k) {
            const int r = rq * 4 + k;
            vbuf[0][bb * VPH + r] = (_Float16)(
                xs0 * first[r] + xs1 * first[64 + r] + xs2 * first[128 + r] + xs3 * first[192 + r]);
        }
    }

    // per-team G pipeline: 8 frags/site at s*32768 + ih*4096 + wv*1024 + lane*16
    half8_t F0[8], F1[8], F2[8];
    const char* gbase = (const char*)gt + wv * 1024 + lane * 16;
    auto LOAD = [&](int s, half8_t* F) {
        const char* p = gbase + (size_t)s * 32768;
#pragma unroll
        for (int ih = 0; ih < 8; ++ih) aload(F[ih], p + ih * 4096);
    };

    // xs pre-read (persistent regs): for site s, col (s+1)*4
    float4_t xs[4];
    auto XRD = [&](int s) {
#pragma unroll
        for (int jj = 0; jj < 4; ++jj)
            xs[jj] = *(const float4_t*)(xbuf + (q * 4 + jj) * XPITCH + (s + 1) * 4);
    };

    // prologue: team0 {0,2,4} (24 out), team1 {1,3} (16 out; site 5 at w0)
    if (team == 0) { LOAD(0, F0); LOAD(2, F1); LOAD(4, F2); XRD(0); }
    else           { LOAD(1, F0); LOAD(3, F1); }
    LBAR();         // vbuf[0] visible (lgkm only; G loads stay in flight)

    // STEP internals — byte-for-byte R8 (minus xs read, pre-read in PREP)
    auto STEP = [&](int s, half8_t* F) {
        const int p = s & 1;
        const _Float16* vr = &vbuf[p][c * VPH];
        half8_t af0 = *(const half8_t*)(vr + q * 8);          // v[c][8q..8q+7]
        half8_t af1 = *(const half8_t*)(vr + 32 + q * 8);     // v[c][32+8q..]

        // invariant: 24 outstanding for this team; oldest 8 = this site's frags
        WAITV(16);
        TIE8(F);

        // wave-local per-batch power-of-2 renorm every 8 sites (team0 sites only)
        if ((s & 7) == 0 && s != 0) {
            float a[16];
#pragma unroll
            for (int k = 0; k < 8; ++k) { a[k] = (float)af0[k]; a[8 + k] = (float)af1[k]; }
            float m = 0.f;
#pragma unroll
            for (int k = 0; k < 16; ++k) m = fmaxf(m, fabsf(a[k]));
            m = fmaxf(m, __shfl_xor(m, 16));   // max over q: all 64 r per batch
            m = fmaxf(m, __shfl_xor(m, 32));
            int e = 0;
            if (m > 0.f) frexpf(m, &e);
            const float sc = ldexpf(1.0f, -e);
#pragma unroll
            for (int k = 0; k < 8; ++k) {
                af0[k] = (_Float16)(a[k] * sc);
                af1[k] = (_Float16)(a[8 + k] * sc);
            }
            if (tid < 16) eacc[tid] += e;   // wave 0 (team0), q=0: lane==c==batch
        }

        float4_t acc[4];
#pragma unroll
        for (int i = 0; i < 4; ++i) {
            float4_t z = {0.f, 0.f, 0.f, 0.f};
            z = __builtin_amdgcn_mfma_f32_16x16x32_f16(af0, F[i * 2 + 0], z, 0, 0, 0);
            z = __builtin_amdgcn_mfma_f32_16x16x32_f16(af1, F[i * 2 + 1], z, 0, 0, 0);
            acc[i] = z;
        }

#pragma unroll
        for (int jj = 0; jj < 4; ++jj) {
            const float vn = xs[jj].x * acc[0][jj] + xs[jj].y * acc[1][jj] +
                             xs[jj].z * acc[2][jj] + xs[jj].w * acc[3][jj];
            vbuf[p ^ 1][(q * 4 + jj) * VPH + wv * 16 + c] = (_Float16)vn;
        }
    };

    // 126 = 21 x 6 windows; per block of 6: team0 STEPs B,B+2,B+4 (F0,F1,F2),
    // team1 STEPs B+1,B+3,B+5. Off-team windows: one 8-LOAD + one XRD.
    // Clamped tail loads are in-bounds dups, drained by final WAITV(0).
    for (int B = 0; B < NSITES; B += 6) {
        // w0
        if (team == 0) STEP(B + 0, F0);
        else { LOAD((B + 5 < NSITES) ? B + 5 : 125, F2); XRD(B + 1); }
        LBAR();
        // w1
        if (team == 1) STEP(B + 1, F0);
        else { LOAD((B + 6 < NSITES) ? B + 6 : 124, F0); XRD(B + 2); }
        LBAR();
        // w2
        if (team == 0) STEP(B + 2, F1);
        else { LOAD((B + 7 < NSITES) ? B + 7 : 125, F0); XRD(B + 3); }
        LBAR();
        // w3
        if (team == 1) STEP(B + 3, F1);
        else { LOAD((B + 8 < NSITES) ? B + 8 : 124, F1); XRD(B + 4); }
        LBAR();
        // w4
        if (team == 0) STEP(B + 4, F2);
        else { LOAD((B + 9 < NSITES) ? B + 9 : 125, F1); XRD(B + 5); }
        LBAR();
        // w5
        if (team == 1) STEP(B + 5, F2);
        else { LOAD((B + 10 < NSITES) ? B + 10 : 124, F2); XRD(B + 6); }
        LBAR();
    }
    WAITV(0);   // drain tail dups

    // final v in vbuf[0] (126 even); out[b] = 2^eacc * sum_r v*last_vec
    if (tid < 256) {
        const int bb = tid >> 4, rq = tid & 15;
        const float x0 = xbuf[bb * XPITCH + 508], x1 = xbuf[bb * XPITCH + 509];
        const float x2 = xbuf[bb * XPITCH + 510], x3 = xbuf[bb * XPITCH + 511];
        float dot = 0.f;
#pragma unroll
        for (int k = 0; k < 4; ++k) {
            const int r = rq * 4 + k;
            const float lv = last[r * 4 + 0] * x0 + last[r * 4 + 1] * x1 +
                             last[r * 4 + 2] * x2 + last[r * 4 + 3] * x3;
            dot += lv * (float)vbuf[0][bb * VPH + r];
        }
#pragma unroll
        for (int o = 8; o > 0; o >>= 1) dot += __shfl_xor(dot, o, 16);
        if (rq == 0) out[b0 + bb] = ldexpf(dot, eacc[bb]);
    }
}

extern "C" void kernel_launch(void* const* d_in, const int* in_sizes, int n_in,
                              void* d_out, int out_size, void* d_ws, size_t ws_size,
                              hipStream_t stream) {
    (void)in_sizes; (void)n_in; (void)out_size; (void)ws_size;
    const float* x     = (const float*)d_in[0];
    const float* first = (const float*)d_in[1];
    const float* mid   = (const float*)d_in[2];
    const float* last  = (const float*)d_in[3];
    float* out = (float*)d_out;
    _Float16* gt = (_Float16*)d_ws;   // 126*2048*16 B = 4,128,768 B

    repack_g<<<1008, 256, 0, stream>>>(mid, gt);
    tt_chain<<<256, 512, 0, stream>>>(x, first, last, gt, out);
}